// Round 6
// baseline (303.512 us; speedup 1.0000x reference)
//
#include <hip/hip_runtime.h>

// Exact-order float32 arithmetic: numpy/jax evaluate left-to-right with no
// FMA contraction. hipcc defaults to -ffp-contract=fast, which would change
// rounding -> possible spike-time shift -> large voltage absmax error.
#pragma clang fp contract(off)

// R19 = R18 (256-260 us/dispatch, absmax 0.0) with the post-resolve FP
// recompute replaced by pure selection, on a 5-lane dual-ballot layout:
//   lane n = neuron n (0=LLBN 1=EBN 2=IFN 3=TN 4=MN); each lane computes
//   BOTH candidate tails v1_0/v1_1 = fmaf(0.25, t6+V{0,1}, v) (parallel ILP)
//   and TWO ballots m0/m1 carry every variant's fire bit.
//   SALU resolve (shallow: whole-mask cselects + const shifts, no dynamic
//   shifts):  nz2 = m0.b0;  z3 = (nz2?m1:m0).b1;  nz4/nz5 = (z3?m1:m0).b2/b3;
//             nz6 = (nz5?m1:m0).b4.
//   ssel (variant-select) = nz2<<1 | z3*0xC | nz5<<4;
//   fm   (fire mask)      = nz2 | z3<<1 | nz4<<2 | nz5<<3 | nz6<<4.
//   Actual state = sel_mask(v1_0,v1_1,ssel) -> sel_mask(.,c,fm); u via fm.
//   Select commutes with the per-lane FP sequence -> bitwise identical to
//   R13/R18's recomputed tail (validated absmax 0.0 lineage R2..R18).
//   Post-ballot VALU chain: 2 cndmasks (was cndmask+add+fmaf+cmp+cndmask).
// z5p is folded into TN's C0a/C0b candidates as before; LLBN's I2 (from
// z2p,z4p) overrides V0 on lane 0 and its V1/ssel bit are never selected.
// Detection semantics (rolling-40 anchor at block tops + Brent pow-2
// fallback, bitwise state equality over {v,u} x 5 lanes + carry bits),
// batched float4 flush, and fill_cycle are R13/R18 verbatim (mask 0x1F).
// R16 (DPP partner-select) and R17 (2-step spec) measured worse/wrong —
// this keeps all selects as SGPR-mask cndmasks, no DPP, no lane pairs.

__device__ __forceinline__ float sel_mask(float a, float b, unsigned long long m) {
    float r;
    // D = m.bit[lane] ? S1 : S0   (VOP3 v_cndmask with SGPR-pair condition)
    asm("v_cndmask_b32 %0, %1, %2, %3" : "=v"(r) : "v"(a), "v"(b), "s"(m));
    return r;
}

__global__ __launch_bounds__(256) void net_sim(const float* __restrict__ mat,
                                               const float* __restrict__ w,
                                               float* __restrict__ out,
                                               int* __restrict__ ws,
                                               int T) {
    __shared__ double red[256];
    const int tid = threadIdx.x;

    // ---- z_plus = sum(input_mat * w0), f32 products accumulated in f64 ----
    const float w0 = w[0];
    double s = 0.0;
    for (int i = tid; i < 127 * 127; i += 256) {
        float p = mat[i] * w0;   // elementwise product rounded to f32 (as ref)
        s += (double)p;
    }
    red[tid] = s;
    __syncthreads();
    #pragma unroll
    for (int off = 128; off > 0; off >>= 1) {
        if (tid < off) red[tid] += red[tid + off];
        __syncthreads();
    }
    if (tid >= 5) return;   // 5 lanes of wave 0 continue; no more barriers

    const float z_plus = (float)red[0];

    const float w2 = w[2], w3 = w[3], w5 = w[5], w6 = w[6], w7 = w[7],
                w8 = w[8], w9 = w[9], w10 = w[10], w11 = w[11];
    const float zp_w1 = z_plus * w[1];
    const float zp_w4 = z_plus * w[4];

    // Validated constant-I set (R2..R18, absmax 0.0). z*w is exactly +0.0f
    // or w; x + (+0.0f) == x for the values involved.
    const float I2_00 = w2 * (zp_w1 - 0.0f) + w3 * 0.0f;   // (z2p, z4p)
    const float I2_10 = w2 * (zp_w1 - 0.0f) + w3 * 1.0f;
    const float I2_01 = w2 * (zp_w1 - w7)   + w3 * 0.0f;
    const float I2_11 = w2 * (zp_w1 - w7)   + w3 * 1.0f;
    const float I3_0  = zp_w4 + 0.0f * w5;
    const float I3_1  = zp_w4 + 1.0f * w5;
    const float I4_0  = 0.0f * w6;
    const float I4_1  = 1.0f * w6;
    const float I5_00 = w9 * (0.0f * w8) + w10 * 0.0f;     // (z3, z5p)
    const float I5_10 = w9 * (1.0f * w8) + w10 * 0.0f;
    const float I5_01 = w9 * (0.0f * w8) + w10 * 1.0f;
    const float I5_11 = w9 * (1.0f * w8) + w10 * 1.0f;
    const float I6_0  = 0.0f * w11;
    const float I6_1  = 1.0f * w11;

    const int lane = tid;  // 0=LLBN 1=EBN 2=IFN 3=TN 4=MN
    const bool is_lane0 = (lane == 0);

    // per-lane params; ka = float(TAU*DT*a) computed in f64 like Python
    const float ka = is_lane0 ? (float)(0.25 * 0.1) : (float)(0.25 * 0.02);
    const float b  = is_lane0 ? -0.075f : (lane == 3 ? 0.2f : 0.25f);
    const float c  = lane <= 1 ? -55.0f : -65.0f;
    const float d  = lane == 1 ? 0.05f : 6.0f;
    float v = is_lane0 ? -60.0f : (lane == 3 ? -70.0f : -64.0f);
    float u = is_lane0 ? 4.5f   : (lane == 3 ? -14.0f : -16.0f);

    // candidate-I constants: variant0/variant1 per lane, for z5p=0(a)/1(b)
    const float C0a = lane == 1 ? I3_0 : lane == 2 ? I4_0
                    : lane == 3 ? I5_00 : lane == 4 ? I6_0 : I2_00;
    const float C0b = lane == 3 ? I5_01 : C0a;
    const float C1a = lane == 1 ? I3_1 : lane == 2 ? I4_1
                    : lane == 3 ? I5_10 : lane == 4 ? I6_1 : 0.0f;
    const float C1b = lane == 3 ? I5_11 : C1a;

    float* __restrict__ psp = out + lane * T;           // spikes row
    float* __restrict__ pvv = out + 5 * T + lane * T;   // volts row

    int z2 = 0, z4 = 0, z5 = 0;   // prev-step bits (z2p, z4p, z5p) — uniform

    // ---- cycle-detection: rolling-40 anchor + Brent pow-2 fallback ----
    float rav = 0.0f, rau = 0.0f; int raz2 = 0, raz4 = 0, raz5 = 0, ra_t = -1;
    float cav = 0.0f, cau = 0.0f; int caz2 = 0, caz4 = 0, caz5 = 0, ca_t = -1;
    int next_coarse = 8;
    int t_det = -1, Pf = 0;
    int blk5 = 0;   // t/8 mod 5; 0 <=> t % 40 == 0

    float zb[8], vb[8];

    int t = 0;
    for (; t + 8 <= T; t += 8) {
        // ---- block top: anchor compares / refresh (R9 semantics) ----
        if (blk5 == 0) {
            if (ra_t >= 0) {
                unsigned long long mv =
                    __ballot(__float_as_uint(v) == __float_as_uint(rav));
                unsigned long long mu =
                    __ballot(__float_as_uint(u) == __float_as_uint(rau));
                if (((mv & mu) & 0x1Full) == 0x1Full &&
                    z2 == raz2 && z4 == raz4 && z5 == raz5) {
                    t_det = t; Pf = t - ra_t;   // Pf == 40
                    break;
                }
            }
            if (t) { rav = v; rau = u; raz2 = z2; raz4 = z4; raz5 = z5; ra_t = t; }
        } else if (ca_t >= 0) {
            unsigned long long mv =
                __ballot(__float_as_uint(v) == __float_as_uint(cav));
            unsigned long long mu =
                __ballot(__float_as_uint(u) == __float_as_uint(cau));
            if (((mv & mu) & 0x1Full) == 0x1Full &&
                z2 == caz2 && z4 == caz4 && z5 == caz5) {
                t_det = t; Pf = t - ca_t;
                break;
            }
        }
        if (t == next_coarse) {
            cav = v; cau = u; caz2 = z2; caz4 = z4; caz5 = z5; ca_t = t;
            next_coarse <<= 1;
        }
        blk5 = (blk5 == 4) ? 0 : (blk5 + 1);

        #pragma unroll
        for (int j = 0; j < 8; ++j) {
            // candidate-I prep from prev-step bits (off critical path)
            float fI2 = z4 ? (z2 ? I2_11 : I2_01) : (z2 ? I2_10 : I2_00);
            float V0 = z5 ? C0b : C0a;
            float V1 = z5 ? C1b : C1a;
            V0 = is_lane0 ? fI2 : V0;

            // common izh head (I-independent)
            float t1 = 0.04f * v;
            float t2 = t1 * v;
            float t3 = 5.0f * v;
            float t4 = t2 + t3;
            float t5 = t4 + 140.0f;
            float t6 = t5 - u;
            float bv = b * v;
            float bvu = bv - u;
            float du = ka * bvu;
            float u1 = u + du;
            float u1d = u1 + d;

            // BOTH candidate tails (parallel ILP); fmaf exact (R18-validated)
            float t7_0 = t6 + V0;
            float t7_1 = t6 + V1;
            float v1_0 = fmaf(0.25f, t7_0, v);
            float v1_1 = fmaf(0.25f, t7_1, v);
            unsigned long long m0 = __ballot(v1_0 >= 30.0f);
            unsigned long long m1 = __ballot(v1_1 >= 30.0f);

            // shallow uniform resolve (whole-mask cselects, const shifts)
            unsigned a0 = (unsigned)m0, a1 = (unsigned)m1;
            int nz2 = (int)(a0 & 1u);                    // LLBN fire (actual)
            unsigned selE = nz2 ? a1 : a0;
            int z3  = (int)((selE >> 1) & 1u);           // EBN fire
            unsigned sel3 = z3 ? a1 : a0;
            int nz4 = (int)((sel3 >> 2) & 1u);           // IFN fire
            int nz5 = (int)((sel3 >> 3) & 1u);           // TN fire
            unsigned selM = nz5 ? a1 : a0;
            int nz6 = (int)((selM >> 4) & 1u);           // MN fire
            unsigned long long ssel =
                (nz2 ? 0x02ull : 0ull) | (z3 ? 0x0Cull : 0ull)
              | (nz5 ? 0x10ull : 0ull);
            unsigned long long fm =
                (nz2 ? 0x01ull : 0ull) | (z3 ? 0x02ull : 0ull)
              | (nz4 ? 0x04ull : 0ull) | (nz5 ? 0x08ull : 0ull)
              | (nz6 ? 0x10ull : 0ull);

            // actual state = pure selection (2 dependent cndmasks)
            float v1s = sel_mask(v1_0, v1_1, ssel);
            v = sel_mask(v1s, c, fm);
            u = sel_mask(u1, u1d, fm);           // z*d is exactly d or +0.0f
            zb[j] = sel_mask(0.0f, 1.0f, fm);
            vb[j] = v;

            z2 = nz2; z4 = nz4; z5 = nz5;
        }
        // batched flush (rows 16B-aligned at t; t % 8 == 0)
        *(float4*)(psp)     = make_float4(zb[0], zb[1], zb[2], zb[3]);
        *(float4*)(psp + 4) = make_float4(zb[4], zb[5], zb[6], zb[7]);
        *(float4*)(pvv)     = make_float4(vb[0], vb[1], vb[2], vb[3]);
        *(float4*)(pvv + 4) = make_float4(vb[4], vb[5], vb[6], vb[7]);
        psp += 8;
        pvv += 8;
    }
    // tail (T not divisible by 8), only when no cycle was detected
    for (; t < T && t_det < 0; ++t) {
        float fI2 = z4 ? (z2 ? I2_11 : I2_01) : (z2 ? I2_10 : I2_00);
        float V0 = z5 ? C0b : C0a;
        float V1 = z5 ? C1b : C1a;
        V0 = is_lane0 ? fI2 : V0;
        float t1 = 0.04f * v;
        float t2 = t1 * v;
        float t3 = 5.0f * v;
        float t4 = t2 + t3;
        float t5 = t4 + 140.0f;
        float t6 = t5 - u;
        float bv = b * v;
        float bvu = bv - u;
        float du = ka * bvu;
        float u1 = u + du;
        float u1d = u1 + d;
        float t7_0 = t6 + V0;
        float t7_1 = t6 + V1;
        float v1_0 = fmaf(0.25f, t7_0, v);
        float v1_1 = fmaf(0.25f, t7_1, v);
        unsigned long long m0 = __ballot(v1_0 >= 30.0f);
        unsigned long long m1 = __ballot(v1_1 >= 30.0f);
        unsigned a0 = (unsigned)m0, a1 = (unsigned)m1;
        int nz2 = (int)(a0 & 1u);
        unsigned selE = nz2 ? a1 : a0;
        int z3  = (int)((selE >> 1) & 1u);
        unsigned sel3 = z3 ? a1 : a0;
        int nz4 = (int)((sel3 >> 2) & 1u);
        int nz5 = (int)((sel3 >> 3) & 1u);
        unsigned selM = nz5 ? a1 : a0;
        int nz6 = (int)((selM >> 4) & 1u);
        unsigned long long ssel =
            (nz2 ? 0x02ull : 0ull) | (z3 ? 0x0Cull : 0ull)
          | (nz5 ? 0x10ull : 0ull);
        unsigned long long fm =
            (nz2 ? 0x01ull : 0ull) | (z3 ? 0x02ull : 0ull)
          | (nz4 ? 0x04ull : 0ull) | (nz5 ? 0x08ull : 0ull)
          | (nz6 ? 0x10ull : 0ull);
        float v1s = sel_mask(v1_0, v1_1, ssel);
        v = sel_mask(v1s, c, fm);
        u = sel_mask(u1, u1d, fm);
        psp[0] = sel_mask(0.0f, 1.0f, fm);
        pvv[0] = v;
        ++psp; ++pvv;
        z2 = nz2; z4 = nz4; z5 = nz5;
    }

    // publish detection result (ws is re-poisoned before every call)
    if (lane == 0) {
        ws[0] = (t_det >= 0) ? 1 : 0;
        ws[1] = t_det;
        ws[2] = Pf;
    }
}

// Fills out[r, t] for t in [t_det, T) with the periodic continuation
// out[r, t_det - P + ((t - t_det) mod P)]. No-op when no cycle was found.
__global__ __launch_bounds__(256) void fill_cycle(float* __restrict__ out,
                                                  const int* __restrict__ ws,
                                                  int T) {
    if (ws[0] == 0) return;
    const int t0 = ws[1];
    const int P  = ws[2];
    const int r  = blockIdx.y;                    // 0..9 (row)
    const float* __restrict__ src = out + (size_t)r * T + (t0 - P);
    float* __restrict__ dst       = out + (size_t)r * T + t0;
    const int n = T - t0;
    for (int i = blockIdx.x * blockDim.x + threadIdx.x; i < n;
         i += gridDim.x * blockDim.x) {
        dst[i] = src[i % P];
    }
}

extern "C" void kernel_launch(void* const* d_in, const int* in_sizes, int n_in,
                              void* d_out, int out_size, void* d_ws, size_t ws_size,
                              hipStream_t stream) {
    const float* mat = (const float*)d_in[0];
    const float* w   = (const float*)d_in[1];
    // out_size = 2 outputs * 5 neurons * T  -> T = out_size/10
    int T = out_size / 10;
    net_sim<<<1, 256, 0, stream>>>(mat, w, (float*)d_out, (int*)d_ws, T);
    dim3 grid(40, 10, 1);
    fill_cycle<<<grid, 256, 0, stream>>>((float*)d_out, (const int*)d_ws, T);
}